// Round 2
// baseline (434.299 us; speedup 1.0000x reference)
//
#include <hip/hip_runtime.h>
#include <hip/hip_bf16.h>
#include <stdint.h>

// ws layout (bytes):
//   0  : unsigned minkey   (monotone float key, atomicMin)
//   4  : unsigned maxkey   (monotone float key, atomicMax)
//   8  : u64 s_fx          (sum,  fixed point 2^20)
//   16 : u64 ss_fx         (sum of squares, fixed point 2^20)
//   32 : unsigned hist[64]
//
// out layout (134 x float32): [mn, mx, num, s, ss, edges[65], counts[64]]
//
// R5 (prev session): wave-contiguous 8KB tiles, 8-deep MLP, coalesced. 434 µs.
// R6: (a) k_reduce: drop float4 vv[8] staging array (rule #20 scratch risk);
//     (b) k_hist: 64 private LDS columns (no same-address atomic serialization).
// R7: resubmit unchanged — R6 never ran (container fail, then broker timeout).

__device__ __forceinline__ unsigned fkey(float f) {
    unsigned u = __float_as_uint(f);
    return (u & 0x80000000u) ? ~u : (u | 0x80000000u);
}
__device__ __forceinline__ float funkey(unsigned k) {
    unsigned u = (k & 0x80000000u) ? (k ^ 0x80000000u) : ~k;
    return __uint_as_float(u);
}

__global__ void k_init(unsigned* minkey, unsigned* maxkey,
                       unsigned long long* sfx, unsigned long long* ssfx,
                       unsigned* ghist) {
    int t = threadIdx.x;
    if (t < 64) ghist[t] = 0u;
    if (t == 64) *minkey = 0xFFFFFFFFu;
    if (t == 65) *maxkey = 0u;
    if (t == 66) *sfx = 0ull;
    if (t == 67) *ssfx = 0ull;
}

__global__ __launch_bounds__(256) void k_reduce(
    const float* __restrict__ x, long long n,
    unsigned* __restrict__ ws_minkey, unsigned* __restrict__ ws_maxkey,
    unsigned long long* __restrict__ ws_sfx, unsigned long long* __restrict__ ws_ssfx)
{
    const float4* __restrict__ x4 = (const float4*)x;
    const long long n4 = n >> 2;                       // # float4
    const int lane = threadIdx.x & 63;
    const int wv   = threadIdx.x >> 6;
    const long long gw     = (long long)blockIdx.x * 4 + wv;   // global wave id
    const long long nwaves = (long long)gridDim.x * 4;
    const long long per_iter = nwaves * 512;           // float4s per grid-iter

    float lmin = INFINITY, lmax = -INFINITY;
    float ls0 = 0.0f, ls1 = 0.0f, lq0 = 0.0f, lq1 = 0.0f;

#define ACC4(v, S, Q) do {                                                 \
        lmin = fminf(lmin, fminf(fminf((v).x, (v).y), fminf((v).z, (v).w))); \
        lmax = fmaxf(lmax, fmaxf(fmaxf((v).x, (v).y), fmaxf((v).z, (v).w))); \
        S += ((v).x + (v).y) + ((v).z + (v).w);                            \
        Q = fmaf((v).x, (v).x, Q); Q = fmaf((v).y, (v).y, Q);              \
        Q = fmaf((v).z, (v).z, Q); Q = fmaf((v).w, (v).w, Q);              \
    } while (0)

    // main loop: wave-contiguous 8 KB tiles, 8 coalesced loads in flight
    for (long long base = gw * 512; base + 512 <= n4; base += per_iter) {
        const float4* __restrict__ p = x4 + base + lane;       // k=0..3: imm 0..3072
        const float4* __restrict__ q = p + 256;                // k=4..7: imm 0..3072
        float4 a0 = p[0], a1 = p[64], a2 = p[128], a3 = p[192];
        float4 a4 = q[0], a5 = q[64], a6 = q[128], a7 = q[192];
        ACC4(a0, ls0, lq0); ACC4(a1, ls1, lq1);
        ACC4(a2, ls0, lq0); ACC4(a3, ls1, lq1);
        ACC4(a4, ls0, lq0); ACC4(a5, ls1, lq1);
        ACC4(a6, ls0, lq0); ACC4(a7, ls1, lq1);
    }
    // remainder float4s (n4 % 512) — block 0 grid-stride
    {
        const long long rem_start = n4 & ~511LL;
        if (blockIdx.x == 0) {
            for (long long i = rem_start + threadIdx.x; i < n4; i += 256) {
                float4 v = x4[i];
                ACC4(v, ls0, lq0);
            }
        }
    }
#undef ACC4
    // scalar tail (n % 4) — block 0
    if (blockIdx.x == 0 && (long long)threadIdx.x < (n & 3)) {
        float v = x[(n4 << 2) + threadIdx.x];
        lmin = fminf(lmin, v); lmax = fmaxf(lmax, v);
        ls0 += v; lq0 = fmaf(v, v, lq0);
    }
    float ls = ls0 + ls1, lss = lq0 + lq1;
    // wave-64 shuffle reduce
    #pragma unroll
    for (int off = 32; off > 0; off >>= 1) {
        lmin = fminf(lmin, __shfl_down(lmin, off, 64));
        lmax = fmaxf(lmax, __shfl_down(lmax, off, 64));
        ls  += __shfl_down(ls,  off, 64);
        lss += __shfl_down(lss, off, 64);
    }
    __shared__ float smin[4], smax[4], ssum[4], ssq[4];
    if ((threadIdx.x & 63) == 0) {
        smin[wv] = lmin; smax[wv] = lmax; ssum[wv] = ls; ssq[wv] = lss;
    }
    __syncthreads();
    if (threadIdx.x == 0) {
        float bmin = fminf(fminf(smin[0], smin[1]), fminf(smin[2], smin[3]));
        float bmax = fmaxf(fmaxf(smax[0], smax[1]), fmaxf(smax[2], smax[3]));
        float bs   = (ssum[0] + ssum[1]) + (ssum[2] + ssum[3]);
        float bss  = (ssq[0]  + ssq[1])  + (ssq[2]  + ssq[3]);
        atomicMin(ws_minkey, fkey(bmin));
        atomicMax(ws_maxkey, fkey(bmax));
        atomicAdd(ws_sfx,  (unsigned long long)(long long)((double)bs  * 1048576.0));
        atomicAdd(ws_ssfx, (unsigned long long)(long long)((double)bss * 1048576.0));
    }
}

__global__ __launch_bounds__(256) void k_hist(
    const float* __restrict__ x, long long n,
    const unsigned* __restrict__ ws_minkey, const unsigned* __restrict__ ws_maxkey,
    unsigned* __restrict__ ghist)
{
    // 64 LDS copies of a 64-bin histogram, hl[bin*64 + lane]:
    // bank = (bin*64+lane)&31 = lane&31 -> always exactly 2 lanes/bank (free,
    // m136), and those 2 lanes use DIFFERENT addresses -> no same-address
    // atomic RMW serialization. 16 KB LDS (128 KB/CU at 8 blocks -> occ same).
    __shared__ unsigned hl[64 * 64];
    for (int i = threadIdx.x; i < 64 * 64; i += 256) hl[i] = 0u;

    const float mn  = funkey(*ws_minkey);
    const float mx  = funkey(*ws_maxkey);
    const float d   = __fsub_rn(mx, mn);
    const float inv = __fdiv_rn(64.0f, d);
    const float base = -mn * inv;   // bin ~= fma(v, inv, base)
    __syncthreads();

    const float4* __restrict__ x4 = (const float4*)x;
    const long long n4 = n >> 2;
    const unsigned c = threadIdx.x & 63u;
    const int lane = threadIdx.x & 63;
    const int wv   = threadIdx.x >> 6;
    const long long gw     = (long long)blockIdx.x * 4 + wv;
    const long long nwaves = (long long)gridDim.x * 4;
    const long long per_iter = nwaves * 512;

    auto binup = [&](float4 v) {
        int j0 = (int)fmaf(v.x, inv, base); j0 = j0 > 63 ? 63 : j0;
        int j1 = (int)fmaf(v.y, inv, base); j1 = j1 > 63 ? 63 : j1;
        int j2 = (int)fmaf(v.z, inv, base); j2 = j2 > 63 ? 63 : j2;
        int j3 = (int)fmaf(v.w, inv, base); j3 = j3 > 63 ? 63 : j3;
        atomicAdd(&hl[(unsigned)j0 * 64u + c], 1u);
        atomicAdd(&hl[(unsigned)j1 * 64u + c], 1u);
        atomicAdd(&hl[(unsigned)j2 * 64u + c], 1u);
        atomicAdd(&hl[(unsigned)j3 * 64u + c], 1u);
    };

    for (long long b = gw * 512; b + 512 <= n4; b += per_iter) {
        const float4* __restrict__ p = x4 + b + lane;
        const float4* __restrict__ q = p + 256;
        float4 a0 = p[0], a1 = p[64], a2 = p[128], a3 = p[192];
        float4 a4 = q[0], a5 = q[64], a6 = q[128], a7 = q[192];
        binup(a0); binup(a1); binup(a2); binup(a3);
        binup(a4); binup(a5); binup(a6); binup(a7);
    }
    // remainder float4s — block 0
    {
        const long long rem_start = n4 & ~511LL;
        if (blockIdx.x == 0)
            for (long long i = rem_start + threadIdx.x; i < n4; i += 256)
                binup(x4[i]);
    }
    // scalar tail — block 0
    if (blockIdx.x == 0 && (long long)threadIdx.x < (n & 3)) {
        float v = x[(n4 << 2) + threadIdx.x];
        int j = (int)fmaf(v, inv, base); j = j > 63 ? 63 : j;
        atomicAdd(&hl[(unsigned)j * 64u + c], 1u);
    }
    __syncthreads();
    if (threadIdx.x < 64) {
        const unsigned b = threadIdx.x;
        unsigned s = 0;
        #pragma unroll
        for (unsigned k = 0; k < 64; ++k)
            s += hl[b * 64u + ((k + b) & 63u)];   // rotated: 2 lanes/bank, conflict-free
        atomicAdd(&ghist[b], s);
    }
}

__global__ void k_fin(const unsigned* ws_minkey, const unsigned* ws_maxkey,
                      const unsigned long long* ws_sfx, const unsigned long long* ws_ssfx,
                      const unsigned* ghist, float* out, float fnum)
{
    const int t = threadIdx.x;
    const float mn = funkey(*ws_minkey);
    const float mx = funkey(*ws_maxkey);
    const float d  = __fsub_rn(mx, mn);
    if (t == 0) out[0] = mn;
    else if (t == 1) out[1] = mx;
    else if (t == 2) out[2] = fnum;
    else if (t == 3) out[3] = (float)((double)(long long)(*ws_sfx)  * 9.5367431640625e-07);
    else if (t == 4) out[4] = (float)((double)(long long)(*ws_ssfx) * 9.5367431640625e-07);
    else if (t >= 5 && t < 70) {
        int i = t - 5;
        // match jnp: edges[i] = f32(mn + f32(f32(mx-mn) * f32(i/64))), unfused
        out[t] = __fadd_rn(mn, __fmul_rn(d, (float)i * 0.015625f));
    } else if (t >= 70 && t < 134) {
        int b = t - 70;
        unsigned cv = ghist[b] + (b == 63 ? 1u : 0u);  // ref adds literal +1 to last bin
        out[t] = (float)cv;
    }
}

extern "C" void kernel_launch(void* const* d_in, const int* in_sizes, int n_in,
                              void* d_out, int out_size, void* d_ws, size_t ws_size,
                              hipStream_t stream)
{
    const float* x = (const float*)d_in[0];
    const long long n = (long long)in_sizes[0];

    unsigned* minkey = (unsigned*)d_ws;
    unsigned* maxkey = minkey + 1;
    unsigned long long* sfx  = (unsigned long long*)((char*)d_ws + 8);
    unsigned long long* ssfx = (unsigned long long*)((char*)d_ws + 16);
    unsigned* ghist = (unsigned*)((char*)d_ws + 32);

    k_init<<<1, 128, 0, stream>>>(minkey, maxkey, sfx, ssfx, ghist);

    const int blocks = 2048;  // 8 blocks/CU, 4 waves each -> exactly 4 main-loop iters
    k_reduce<<<blocks, 256, 0, stream>>>(x, n, minkey, maxkey, sfx, ssfx);
    k_hist<<<blocks, 256, 0, stream>>>(x, n, minkey, maxkey, ghist);
    k_fin<<<1, 192, 0, stream>>>(minkey, maxkey, sfx, ssfx, ghist,
                                 (float*)d_out, (float)n);
}